// Round 2
// baseline (462.775 us; speedup 1.0000x reference)
//
#include <hip/hip_runtime.h>
#include <math.h>

// Problem constants
#define B_ 32
#define C_ 512
#define G_ 32
#define N_ 1024          // H*W
#define OC3_ 1536        // 3*C
#define EPS_ 1e-5f

typedef __attribute__((ext_vector_type(8))) short short8;
typedef __attribute__((ext_vector_type(4))) float f32x4;

// fp32 -> bf16 RNE
__device__ inline unsigned short f2bf(float f) {
    unsigned u = __builtin_bit_cast(unsigned, f);
    u += 0x7fffu + ((u >> 16) & 1u);
    return (unsigned short)(u >> 16);
}
__device__ inline unsigned pack2(float lo, float hi) {
    return (unsigned)f2bf(lo) | ((unsigned)f2bf(hi) << 16);
}
__device__ inline float bf2f(unsigned short u) {
    return __builtin_bit_cast(float, ((unsigned)u) << 16);
}

// async global->LDS 16 B per lane (gfx950). LDS dest = wave-uniform base +
// lane*16 (hardware requirement); source address is per-lane, so the LDS
// swizzle is achieved by PRE-SWIZZLING the global source (rule #21).
typedef const __attribute__((address_space(1))) unsigned int* gas_u32;
typedef __attribute__((address_space(3))) unsigned int* las_u32;
__device__ __forceinline__ void cp16(unsigned short* lds, const unsigned short* g) {
    __builtin_amdgcn_global_load_lds((gas_u32)g, (las_u32)lds, 16, 0, 0);
}

// ---------------------------------------------------------------------------
// GroupNorm statistics. One block per (b,g): 16 ch x 1024 = 16384 floats.
// ---------------------------------------------------------------------------
__global__ __launch_bounds__(256) void gn_stats_kernel(
    const float* __restrict__ x, float* __restrict__ stats)
{
    int bg = blockIdx.x;
    const float4* xv = (const float4*)(x + (size_t)bg * 16 * N_);
    float s = 0.f, ss = 0.f;
    for (int i = threadIdx.x; i < 4096; i += 256) {
        float4 v = xv[i];
        s  += v.x + v.y + v.z + v.w;
        ss += v.x*v.x + v.y*v.y + v.z*v.z + v.w*v.w;
    }
    __shared__ float r1[256], r2[256];
    r1[threadIdx.x] = s; r2[threadIdx.x] = ss;
    __syncthreads();
    for (int off = 128; off > 0; off >>= 1) {
        if (threadIdx.x < off) {
            r1[threadIdx.x] += r1[threadIdx.x + off];
            r2[threadIdx.x] += r2[threadIdx.x + off];
        }
        __syncthreads();
    }
    if (threadIdx.x == 0) {
        float mean = r1[0] * (1.f / 16384.f);
        float var  = r2[0] * (1.f / 16384.f) - mean * mean;
        stats[bg * 2 + 0] = mean;
        stats[bg * 2 + 1] = rsqrtf(var + EPS_);
    }
}

// ---------------------------------------------------------------------------
// fp32 -> bf16 elementwise convert (weights; once per launch).
// ---------------------------------------------------------------------------
__global__ __launch_bounds__(256) void cvt_bf16_kernel(
    const float* __restrict__ src, unsigned short* __restrict__ dst, int n4)
{
    int i = blockIdx.x * 256 + threadIdx.x;
    if (i >= n4) return;
    float4 v = ((const float4*)src)[i];
    uint2 o; o.x = pack2(v.x, v.y); o.y = pack2(v.z, v.w);
    ((uint2*)dst)[i] = o;
}

// ---------------------------------------------------------------------------
// hhatT producer: x[b][c][n] fp32 (coalesced reads) -> GN affine ->
// hhatT[bz][n][c] bf16 via 64x64 LDS tile transpose.
// ---------------------------------------------------------------------------
__global__ __launch_bounds__(256) void hhatT_kernel(
    const float* __restrict__ x, const float* __restrict__ stats,
    const float* __restrict__ nw, const float* __restrict__ nbias,
    unsigned short* __restrict__ hhatT, long sH, int b0)
{
    int bz = blockIdx.z, b = b0 + bz;
    int nt = blockIdx.x * 64, ct = blockIdx.y * 64;
    const float* xb = x + (size_t)b * C_ * N_;
    const float* st = stats + b * 2 * G_;

    __shared__ float T[64][65];
    int tid = threadIdx.x;

    #pragma unroll
    for (int p = 0; p < 4; ++p) {
        int c = p * 16 + (tid >> 4);
        int n4 = (tid & 15) * 4;
        float4 v = *(const float4*)&xb[(size_t)(ct + c) * N_ + nt + n4];
        int g = (ct + c) >> 4;
        float w0 = nw[ct + c] * st[g * 2 + 1];
        float bb = nbias[ct + c] - st[g * 2] * w0;
        T[c][n4]   = v.x * w0 + bb;
        T[c][n4+1] = v.y * w0 + bb;
        T[c][n4+2] = v.z * w0 + bb;
        T[c][n4+3] = v.w * w0 + bb;
    }
    __syncthreads();
    #pragma unroll
    for (int p = 0; p < 2; ++p) {
        int n  = p * 32 + (tid >> 3);
        int c8 = (tid & 7) * 8;
        short8 s;
        #pragma unroll
        for (int u = 0; u < 8; ++u) s[u] = (short)f2bf(T[c8 + u][n]);
        *(short8*)&hhatT[(size_t)bz * sH + (size_t)(nt + n) * C_ + ct + c8] = s;
    }
}

// ---------------------------------------------------------------------------
// R11: 256x256 GEMM, 8-phase-style schedule (T2+T3+T4+T5 port of the
// verified 8-phase template, adapted to BK=32 for short K).
//
//   D[row][col] = sum_k A[row][k] * B[col][k]   (+ epilogue)
//
// Geometry: 8 waves (2M x 4N), per-wave output 128x64 = 8x4 16x16 frags.
// LDS: 4-buffer ring x (A 16KB + B 16KB) = 128 KB. K-tile t -> buf[t&3].
// Staging: K-tile t+2 staged during K-tile t (phase0: A-half, phase1: B-half;
//   2 cp16/thread each). Stage->consume distance = 4 phases.
// Counted vmcnt ledger (cp16 units/thread): prologue issues 8 (tiles 0,1),
//   vmcnt(4)+barrier publishes tile 0. End of tile t: outstanding =
//   4 (tile t+1) + 4 (tile t+2 if staged) -> vmcnt(4) retires tile t+1's
//   (vmcnt(0) only at t==nt-2, where nothing was staged during t). Never 0
//   in steady state (T4).
// Phase: {ds_read frags || 2 cp16} -> s_barrier -> lgkmcnt(0)+sched_barrier
//   (rule #18) -> setprio(1) -> 16 MFMA -> setprio(0) [-> vmcnt] -> s_barrier.
// Swizzle (T2, rule #21 both-sides): phys_chunk = k_chunk ^ ((row>>1)&3),
//   16B chunks in a 64B row. Applied on the pre-swizzled cp16 SOURCE
//   (gchunk = (l&3)^((l>>3)&3), row = w*32+i*16+(l>>2), so (row>>1)&3 =
//   (l>>3)&3) and on frag reads (sel = (lm>>1)&3; row base is a multiple of
//   16 so sel is per-thread constant). Same involution as the verified
//   128^2 kernel (conflicts measured 0); reduces frag reads to 2-way = free.
// Buffer-overwrite race: buf[(t+2)&3] last read as tile t-2, whose reads
//   are lgkm-complete before >=2 intervening barriers precede the stage.
// XCD swizzle: unchanged (batch -> XCD when nbz%8==0).
// EPI: 0 bf16 +bias[col] | 1 bf16 +bias[row] | 2 bf16 *scale | 3 bf16
//      4 fp32 +bias[row]+aux (residual)
// ---------------------------------------------------------------------------
template<int EPI>
__global__ __launch_bounds__(512) void gemm256(
    const unsigned short* __restrict__ A, long sA, int lda,
    const unsigned short* __restrict__ B, long sB, int ldb,
    void* __restrict__ Dv, long sD, int ldd,
    const float* __restrict__ bias,
    const float* __restrict__ aux, long sAux,
    int K, float scale, int gx, int gy, int nbz)
{
    int bid = blockIdx.x;
    int nbpb = gx * gy;
    int bx, by, bz;
    if ((nbz & 7) == 0) {
        int xcd = bid & 7;
        int rest = bid >> 3;
        int local = rest % nbpb;
        int bg = rest / nbpb;
        bz = bg * 8 + xcd;
        bx = local % gx;
        by = local / gx;
    } else {
        bz = bid / nbpb;
        int local = bid % nbpb;
        bx = local % gx;
        by = local / gx;
    }

    const unsigned short* Ab = A + (size_t)bz * sA + (size_t)bx * 256 * lda;
    const unsigned short* Bb = B + (size_t)bz * sB + (size_t)by * 256 * ldb;

    // [buf][A=0/B=1][256 rows * 32 k] bf16 = 16 KB per half, 128 KB total
    __shared__ __align__(16) unsigned short lds[4][2][8192];

    int tid = threadIdx.x;
    int w = tid >> 6, l = tid & 63;
    int wm = w >> 2, wn = w & 3;            // 2 x 4 wave grid
    int wrow = wm * 128, wcol = wn * 64;    // wave's output sub-tile origin
    int lm = l & 15, q = l >> 4;

    f32x4 acc[8][4];
    #pragma unroll
    for (int i = 0; i < 8; ++i)
        #pragma unroll
        for (int j = 0; j < 4; ++j) acc[i][j] = (f32x4)(0.f);

    // ---- staging addressing (pre-swizzled global source, linear LDS dest)
    int srow = l >> 2;                         // 0..15 within a 16-row strip
    int gch  = (l & 3) ^ ((l >> 3) & 3);       // swizzled source chunk
    const unsigned short* aS0 = Ab + (size_t)(w * 32 +      srow) * lda + gch * 8;
    const unsigned short* aS1 = Ab + (size_t)(w * 32 + 16 + srow) * lda + gch * 8;
    const unsigned short* bS0 = Bb + (size_t)(w * 32 +      srow) * ldb + gch * 8;
    const unsigned short* bS1 = Bb + (size_t)(w * 32 + 16 + srow) * ldb + gch * 8;
    int ld0 = w * 1024 + l * 8;                // LDS dest (shorts), strip 0
    int ld1 = w * 1024 + 512 + l * 8;          // strip 1

    // ---- fragment read addressing (swizzled chunk, per-thread constant)
    int fch = (q ^ ((lm >> 1) & 3)) * 8;       // phys chunk in shorts
    int aro = (wrow + lm) * 32 + fch;          // + (ph*64 + m*16)*32 imm
    int bro = (wcol + lm) * 32 + fch;          // + (n*16)*32 imm

    // ---- prologue: stage K-tiles 0,1; publish tile 0 (vmcnt 8 -> 4)
    cp16(&lds[0][0][ld0], aS0);      cp16(&lds[0][0][ld1], aS1);
    cp16(&lds[0][1][ld0], bS0);      cp16(&lds[0][1][ld1], bS1);
    cp16(&lds[1][0][ld0], aS0 + 32); cp16(&lds[1][0][ld1], aS1 + 32);
    cp16(&lds[1][1][ld0], bS0 + 32); cp16(&lds[1][1][ld1], bS1 + 32);
    asm volatile("s_waitcnt vmcnt(4)" ::: "memory");
    __builtin_amdgcn_s_barrier();

    int nt = K >> 5;                 // K-tiles of 32; >= 16 at all call sites
    for (int t = 0; t < nt; ++t) {
        const unsigned short* At = &lds[t & 3][0][0];
        const unsigned short* Bt = &lds[t & 3][1][0];
        bool stg = (t + 2) < nt;
        int sb = (t + 2) & 3;
        int so = (t + 2) * 32;

        short8 bf[4];
        #pragma unroll
        for (int ph = 0; ph < 2; ++ph) {
            short8 af[4];
            #pragma unroll
            for (int m = 0; m < 4; ++m)
                af[m] = *(const short8*)&At[aro + (ph * 64 + m * 16) * 32];
            if (ph == 0) {
                #pragma unroll
                for (int n = 0; n < 4; ++n)
                    bf[n] = *(const short8*)&Bt[bro + n * 16 * 32];
                if (stg) {
                    cp16(&lds[sb][0][ld0], aS0 + so);
                    cp16(&lds[sb][0][ld1], aS1 + so);
                }
            } else {
                if (stg) {
                    cp16(&lds[sb][1][ld0], bS0 + so);
                    cp16(&lds[sb][1][ld1], bS1 + so);
                }
            }
            __builtin_amdgcn_s_barrier();
            asm volatile("s_waitcnt lgkmcnt(0)" ::: "memory");
            __builtin_amdgcn_sched_barrier(0);
            __builtin_amdgcn_s_setprio(1);
            #pragma unroll
            for (int m = 0; m < 4; ++m)
                #pragma unroll
                for (int n = 0; n < 4; ++n)
                    acc[ph * 4 + m][n] = __builtin_amdgcn_mfma_f32_16x16x32_bf16(
                        af[m], bf[n], acc[ph * 4 + m][n], 0, 0, 0);
            __builtin_amdgcn_s_setprio(0);
            __builtin_amdgcn_sched_barrier(0);
            if (ph == 1 && t + 1 < nt) {
                // publish tile t+1: retire its 4 stages; keep tile t+2's
                // 4 in flight (T4: never drain to 0 while staging continues)
                if (t + 2 < nt) asm volatile("s_waitcnt vmcnt(4)" ::: "memory");
                else            asm volatile("s_waitcnt vmcnt(0)" ::: "memory");
            }
            __builtin_amdgcn_s_barrier();
        }
    }

    int grow = bx * 256 + wrow;
    int gcol = by * 256 + wcol;

    #pragma unroll
    for (int n = 0; n < 4; ++n) {
        int col = gcol + n * 16 + lm;
        float cb = (EPI == 0) ? bias[col] : 0.f;
        #pragma unroll
        for (int mi = 0; mi < 8; ++mi) {
            #pragma unroll
            for (int r = 0; r < 4; ++r) {
                int row = grow + mi * 16 + q * 4 + r;
                float vle = acc[mi][n][r];
                if constexpr (EPI == 0) {
                    vle += cb;
                    ((unsigned short*)Dv)[(size_t)bz * sD + (size_t)row * ldd + col] = f2bf(vle);
                } else if constexpr (EPI == 1) {
                    vle += bias[row];
                    ((unsigned short*)Dv)[(size_t)bz * sD + (size_t)row * ldd + col] = f2bf(vle);
                } else if constexpr (EPI == 2) {
                    ((unsigned short*)Dv)[(size_t)bz * sD + (size_t)row * ldd + col] = f2bf(vle * scale);
                } else if constexpr (EPI == 3) {
                    ((unsigned short*)Dv)[(size_t)bz * sD + (size_t)row * ldd + col] = f2bf(vle);
                } else {
                    vle += bias[row] + aux[(size_t)bz * sAux + (size_t)row * ldd + col];
                    ((float*)Dv)[(size_t)bz * sD + (size_t)row * ldd + col] = vle;
                }
            }
        }
    }
}

// ---------------------------------------------------------------------------
// Softmax: in-place on bf16 scores. One WAVE per row (16 elems/lane),
// shuffle reductions, no barriers. Block = 4 waves = 4 rows.
// ---------------------------------------------------------------------------
__global__ __launch_bounds__(256) void softmax_kernel(
    unsigned short* __restrict__ sc, long sSc)
{
    int bz = blockIdx.y;
    int row = blockIdx.x * 4 + (threadIdx.x >> 6);
    int lane = threadIdx.x & 63;
    unsigned short* p = sc + (size_t)bz * sSc + (size_t)row * N_ + lane * 16;

    short8 s0 = *(const short8*)p;
    short8 s1 = *(const short8*)(p + 8);
    float v[16];
    #pragma unroll
    for (int i = 0; i < 8; ++i) {
        v[i]     = bf2f((unsigned short)s0[i]);
        v[8 + i] = bf2f((unsigned short)s1[i]);
    }
    float m = v[0];
    #pragma unroll
    for (int i = 1; i < 16; ++i) m = fmaxf(m, v[i]);
    #pragma unroll
    for (int off = 32; off > 0; off >>= 1) m = fmaxf(m, __shfl_xor(m, off, 64));

    float sum = 0.f;
    #pragma unroll
    for (int i = 0; i < 16; ++i) { v[i] = __expf(v[i] - m); sum += v[i]; }
    #pragma unroll
    for (int off = 32; off > 0; off >>= 1) sum += __shfl_xor(sum, off, 64);
    float inv = 1.f / sum;

    short8 o0, o1;
    #pragma unroll
    for (int i = 0; i < 8; ++i) {
        o0[i] = (short)f2bf(v[i] * inv);
        o1[i] = (short)f2bf(v[8 + i] * inv);
    }
    *(short8*)p = o0;
    *(short8*)(p + 8) = o1;
}

// ---------------------------------------------------------------------------
extern "C" void kernel_launch(void* const* d_in, const int* in_sizes, int n_in,
                              void* d_out, int out_size, void* d_ws, size_t ws_size,
                              hipStream_t stream) {
    const float* x      = (const float*)d_in[0];
    const float* norm_w = (const float*)d_in[1];
    const float* norm_b = (const float*)d_in[2];
    const float* qkv_w  = (const float*)d_in[3];
    const float* qkv_b  = (const float*)d_in[4];
    const float* proj_w = (const float*)d_in[5];
    const float* proj_b = (const float*)d_in[6];
    float* out = (float*)d_out;

    // Fixed region: stats (8 KB) + bf16 weights (2 MB).
    char* ws = (char*)d_ws;
    float* stats = (float*)ws;
    unsigned short* wqkv  = (unsigned short*)(ws + 8192);   // 1536x512
    unsigned short* wproj = wqkv + (size_t)OC3_ * C_;       // 512x512
    char* base = (char*)(wproj + (size_t)C_ * C_);
    const size_t fixed = 8192 + (size_t)OC3_ * C_ * 2 + (size_t)C_ * C_ * 2;

    // Per-batch aliased region: 6 MB.
    //   [0,2M)  qkT bf16 [n][1024]
    //   [2,3M)  v bf16 [c][n]
    //   [3,4M)  hhatT bf16 [n][c]  -> after GEMM2 reused as houtT bf16 [n][c]
    //   [4,6M)  sc bf16 [n][m]     -> softmax in-place -> attn
    const size_t REG = 6u << 20;
    const long RSH = (long)(REG / 2);         // region stride in shorts

    size_t avail = ws_size > fixed ? ws_size - fixed : 0;
    int chunk = (int)(avail / REG);
    if (chunk < 1) chunk = 1;
    if (chunk > B_) chunk = B_;

    gn_stats_kernel<<<dim3(B_ * G_), dim3(256), 0, stream>>>(x, stats);
    cvt_bf16_kernel<<<dim3((OC3_ * C_ / 4 + 255) / 256), dim3(256), 0, stream>>>(
        qkv_w, wqkv, OC3_ * C_ / 4);
    cvt_bf16_kernel<<<dim3((C_ * C_ / 4 + 255) / 256), dim3(256), 0, stream>>>(
        proj_w, wproj, C_ * C_ / 4);

    const float scale = 0.044194173824159216f;  // 512^-0.5

    unsigned short* qkT   = (unsigned short*)base;
    unsigned short* vbuf  = (unsigned short*)(base + (2u << 20));
    unsigned short* hhatT = (unsigned short*)(base + (3u << 20));
    unsigned short* houtT = (unsigned short*)(base + (3u << 20)); // aliases hhatT
    unsigned short* sc    = (unsigned short*)(base + (4u << 20)); // scores/attn

    for (int b0 = 0; b0 < B_; b0 += chunk) {
        int nb = B_ - b0 < chunk ? B_ - b0 : chunk;

        hhatT_kernel<<<dim3(N_/64, C_/64, nb), dim3(256), 0, stream>>>(
            x, stats, norm_w, norm_b, hhatT, RSH, b0);

        // GEMM1a: qkT[n][o] = hhatT[n][:] . Wqk[o][:]   (o in [0,1024))
        gemm256<0><<<dim3(4 * 4 * nb), dim3(512), 0, stream>>>(
            hhatT, RSH, C_,  wqkv, 0, C_,
            qkT, RSH, 1024,  qkv_b, nullptr, 0, C_, 0.f, 4, 4, nb);

        // GEMM1b: v[c][n] = Wv[c][:] . hhatT[n][:]
        gemm256<1><<<dim3(2 * 4 * nb), dim3(512), 0, stream>>>(
            wqkv + (size_t)1024 * C_, 0, C_,  hhatT, RSH, C_,
            vbuf, RSH, N_,  qkv_b + 1024, nullptr, 0, C_, 0.f, 2, 4, nb);

        // GEMM2: sc[n][m] = bf16( scale * qkT[n][0:512] . qkT[m][512:1024] )
        gemm256<2><<<dim3(4 * 4 * nb), dim3(512), 0, stream>>>(
            qkT, RSH, 1024,  qkT + 512, RSH, 1024,
            sc, RSH, N_,  nullptr, nullptr, 0, C_, scale, 4, 4, nb);

        softmax_kernel<<<dim3(N_/4, nb), dim3(256), 0, stream>>>(sc, RSH);

        // GEMM3: houtT[n][c] = attn[n][:] . v[c][:]   (K = 1024)
        gemm256<3><<<dim3(4 * 2 * nb), dim3(512), 0, stream>>>(
            sc, RSH, N_,  vbuf, RSH, N_,
            houtT, RSH, C_,  nullptr, nullptr, 0, N_, 0.f, 4, 2, nb);

        // GEMM4: out[o][n] = pw[o][:] . houtT[n][:] + pb[o] + x[o][n]
        gemm256<4><<<dim3(2 * 4 * nb), dim3(512), 0, stream>>>(
            wproj, 0, C_,  houtT, RSH, C_,
            out + (size_t)b0 * C_ * N_, (long)C_ * N_, N_,
            proj_b, x + (size_t)b0 * C_ * N_, (long)C_ * N_, C_, 0.f, 2, 4, nb);
    }
}

// Round 3
// 382.434 us; speedup vs baseline: 1.2101x; 1.2101x over previous
//
#include <hip/hip_runtime.h>
#include <math.h>

// Problem constants
#define B_ 32
#define C_ 512
#define G_ 32
#define N_ 1024          // H*W
#define OC3_ 1536        // 3*C
#define EPS_ 1e-5f

typedef __attribute__((ext_vector_type(8))) short short8;
typedef __attribute__((ext_vector_type(4))) float f32x4;

// fp32 -> bf16 RNE
__device__ inline unsigned short f2bf(float f) {
    unsigned u = __builtin_bit_cast(unsigned, f);
    u += 0x7fffu + ((u >> 16) & 1u);
    return (unsigned short)(u >> 16);
}
__device__ inline unsigned pack2(float lo, float hi) {
    return (unsigned)f2bf(lo) | ((unsigned)f2bf(hi) << 16);
}
__device__ inline float bf2f(unsigned short u) {
    return __builtin_bit_cast(float, ((unsigned)u) << 16);
}

// async global->LDS 16 B per lane (gfx950). LDS dest = wave-uniform base +
// lane*16; all call sites use &lds[tid*8] (shorts).
typedef const __attribute__((address_space(1))) unsigned int* gas_u32;
typedef __attribute__((address_space(3))) unsigned int* las_u32;
__device__ __forceinline__ void cp16(unsigned short* lds, const unsigned short* g) {
    __builtin_amdgcn_global_load_lds((gas_u32)g, (las_u32)lds, 16, 0, 0);
}

// ---------------------------------------------------------------------------
// GroupNorm statistics. One block per (b,g): 16 ch x 1024 = 16384 floats.
// ---------------------------------------------------------------------------
__global__ __launch_bounds__(256) void gn_stats_kernel(
    const float* __restrict__ x, float* __restrict__ stats)
{
    int bg = blockIdx.x;
    const float4* xv = (const float4*)(x + (size_t)bg * 16 * N_);
    float s = 0.f, ss = 0.f;
    for (int i = threadIdx.x; i < 4096; i += 256) {
        float4 v = xv[i];
        s  += v.x + v.y + v.z + v.w;
        ss += v.x*v.x + v.y*v.y + v.z*v.z + v.w*v.w;
    }
    __shared__ float r1[256], r2[256];
    r1[threadIdx.x] = s; r2[threadIdx.x] = ss;
    __syncthreads();
    for (int off = 128; off > 0; off >>= 1) {
        if (threadIdx.x < off) {
            r1[threadIdx.x] += r1[threadIdx.x + off];
            r2[threadIdx.x] += r2[threadIdx.x + off];
        }
        __syncthreads();
    }
    if (threadIdx.x == 0) {
        float mean = r1[0] * (1.f / 16384.f);
        float var  = r2[0] * (1.f / 16384.f) - mean * mean;
        stats[bg * 2 + 0] = mean;
        stats[bg * 2 + 1] = rsqrtf(var + EPS_);
    }
}

// ---------------------------------------------------------------------------
// fp32 -> bf16 elementwise convert (weights; once per launch).
// ---------------------------------------------------------------------------
__global__ __launch_bounds__(256) void cvt_bf16_kernel(
    const float* __restrict__ src, unsigned short* __restrict__ dst, int n4)
{
    int i = blockIdx.x * 256 + threadIdx.x;
    if (i >= n4) return;
    float4 v = ((const float4*)src)[i];
    uint2 o; o.x = pack2(v.x, v.y); o.y = pack2(v.z, v.w);
    ((uint2*)dst)[i] = o;
}

// ---------------------------------------------------------------------------
// hhatT producer: x[b][c][n] fp32 (coalesced reads) -> GN affine ->
// hhatT[bz][n][c] bf16 via 64x64 LDS tile transpose.
// ---------------------------------------------------------------------------
__global__ __launch_bounds__(256) void hhatT_kernel(
    const float* __restrict__ x, const float* __restrict__ stats,
    const float* __restrict__ nw, const float* __restrict__ nbias,
    unsigned short* __restrict__ hhatT, long sH, int b0)
{
    int bz = blockIdx.z, b = b0 + bz;
    int nt = blockIdx.x * 64, ct = blockIdx.y * 64;
    const float* xb = x + (size_t)b * C_ * N_;
    const float* st = stats + b * 2 * G_;

    __shared__ float T[64][65];
    int tid = threadIdx.x;

    #pragma unroll
    for (int p = 0; p < 4; ++p) {
        int c = p * 16 + (tid >> 4);
        int n4 = (tid & 15) * 4;
        float4 v = *(const float4*)&xb[(size_t)(ct + c) * N_ + nt + n4];
        int g = (ct + c) >> 4;
        float w0 = nw[ct + c] * st[g * 2 + 1];
        float bb = nbias[ct + c] - st[g * 2] * w0;
        T[c][n4]   = v.x * w0 + bb;
        T[c][n4+1] = v.y * w0 + bb;
        T[c][n4+2] = v.z * w0 + bb;
        T[c][n4+3] = v.w * w0 + bb;
    }
    __syncthreads();
    #pragma unroll
    for (int p = 0; p < 2; ++p) {
        int n  = p * 32 + (tid >> 3);
        int c8 = (tid & 7) * 8;
        short8 s;
        #pragma unroll
        for (int u = 0; u < 8; ++u) s[u] = (short)f2bf(T[c8 + u][n]);
        *(short8*)&hhatT[(size_t)bz * sH + (size_t)(nt + n) * C_ + ct + c8] = s;
    }
}

// ---------------------------------------------------------------------------
// 128x128 GEMM: D[row][col] = sum_k A[row][k] * B[col][k]  (+ epilogue)
// BK=32, 4 waves (2x2 of 64x64). PROVEN R9 K-loop (dbuf global_load_lds,
// XOR chunk swizzle, conflicts=0). R10 counted-vmcnt neutral, R11 256^2
// 8-phase regressed -- both reverted.
//
// R12: LDS-STAGED COALESCED EPILOGUE. Old epilogue: 64 scalar 2-B/4-B stores
// per thread in 32-64-B scattered bursts; counters showed write amplification
// (W=95 MB for <=67 MB logical on the fp32 path) and ~1.9 TB/s effective BW.
// Now: acc -> LDS (reusing the 32 KB staging buffers after a barrier;
// q-XOR chunk swizzle makes writes 2-way word-paired = free, reads linear
// conflict-free) -> full-wave short8/float4 bursts (1 KB contiguous / wave
// instr). EPI4 also reads aux (residual) as coalesced float4.
//
// XCD-LOCALITY SWIZZLE: when nbz%8==0, bid%8 == batch%8 so each batch's
// blocks stay on one XCD's 4 MB L2.
// EPI: 0 bf16 +bias[col] | 1 bf16 +bias[row] | 2 bf16 *scale | 3 bf16
//      4 fp32 +bias[row]+aux (residual)
// ---------------------------------------------------------------------------
template<int EPI>
__global__ __launch_bounds__(256) void gemm128(
    const unsigned short* __restrict__ A, long sA, int lda,
    const unsigned short* __restrict__ B, long sB, int ldb,
    void* __restrict__ Dv, long sD, int ldd,
    const float* __restrict__ bias,
    const float* __restrict__ aux, long sAux,
    int K, float scale, int gx, int gy, int nbz)
{
    int bid = blockIdx.x;
    int nbpb = gx * gy;
    int bx, by, bz;
    if ((nbz & 7) == 0) {
        int xcd = bid & 7;
        int rest = bid >> 3;
        int local = rest % nbpb;
        int bg = rest / nbpb;
        bz = bg * 8 + xcd;
        bx = local % gx;
        by = local / gx;
    } else {
        bz = bid / nbpb;
        int local = bid % nbpb;
        bx = local % gx;
        by = local / gx;
    }

    const unsigned short* Ab = A + (size_t)bz * sA + (size_t)bx * 128 * lda;
    const unsigned short* Bb = B + (size_t)bz * sB + (size_t)by * 128 * ldb;

    // 4 x 8 KB: [0],[1] = A dbuf; [2],[3] = B dbuf. Reused by the epilogue
    // as a 32 KB output staging tile.
    __shared__ __align__(16) unsigned short smem[4][4096];

    int tid = threadIdx.x;
    int w = tid >> 6, lane = tid & 63;
    int lm = lane & 15, q = lane >> 4;
    int wrow = (w >> 1) * 64, wcol = (w & 1) * 64;

    f32x4 acc[4][4];
    #pragma unroll
    for (int i = 0; i < 4; ++i)
        #pragma unroll
        for (int j = 0; j < 4; ++j) acc[i][j] = (f32x4)(0.f);

    int srow = tid >> 2;                              // staging row (0..63)
    int skc  = (((tid & 3) ^ ((tid >> 3) & 3))) * 8;  // swizzled global chunk
    int fco  = (q ^ ((lm >> 1) & 3)) * 8;             // frag physical chunk

    const unsigned short* a0p = Ab + (size_t)srow        * lda + skc;
    const unsigned short* a1p = Ab + (size_t)(64 + srow) * lda + skc;
    const unsigned short* b0p = Bb + (size_t)srow        * ldb + skc;
    const unsigned short* b1p = Bb + (size_t)(64 + srow) * ldb + skc;

    // prologue: stage tile 0 into buffer 0
    cp16(&smem[0][tid * 8],        a0p);
    cp16(&smem[0][2048 + tid * 8], a1p);
    cp16(&smem[2][tid * 8],        b0p);
    cp16(&smem[2][2048 + tid * 8], b1p);

    int nIter = K >> 5;
    for (int it = 0; it < nIter; ++it) {
        int cur = it & 1;
        __syncthreads();   // drains tile-it DMA (in flight since iter it-1)
        if (it + 1 < nIter) {
            int off = (it + 1) * 32;
            int nxt = cur ^ 1;
            cp16(&smem[nxt][tid * 8],            a0p + off);
            cp16(&smem[nxt][2048 + tid * 8],     a1p + off);
            cp16(&smem[2 + nxt][tid * 8],        b0p + off);
            cp16(&smem[2 + nxt][2048 + tid * 8], b1p + off);
        }
        short8 af[4], bf[4];
        #pragma unroll
        for (int i = 0; i < 4; ++i)
            af[i] = *(const short8*)&smem[cur][(wrow + i * 16 + lm) * 32 + fco];
        #pragma unroll
        for (int j = 0; j < 4; ++j)
            bf[j] = *(const short8*)&smem[2 + cur][(wcol + j * 16 + lm) * 32 + fco];
        #pragma unroll
        for (int i = 0; i < 4; ++i)
            #pragma unroll
            for (int j = 0; j < 4; ++j)
                acc[i][j] = __builtin_amdgcn_mfma_f32_16x16x32_bf16(
                    af[i], bf[j], acc[i][j], 0, 0, 0);
    }

    // ----------------------- coalesced epilogue ----------------------------
    __syncthreads();   // all waves done with staging LDS; safe to reuse

    if constexpr (EPI != 4) {
        // bf16: stage 128x128 tile (32 KB). Writer: (lr,lc) ->
        // Ts[lr*128 + (lc ^ (q<<3))], q=(lr>>2)&3. Reader: linear per-wave
        // 1 KB with uniform XOR key -> conflict-free both sides.
        unsigned short* Ts = &smem[0][0];
        #pragma unroll
        for (int j = 0; j < 4; ++j) {
            int lc = wcol + j * 16 + lm;
            float cb = (EPI == 0) ? bias[by * 128 + lc] : 0.f;
            #pragma unroll
            for (int i = 0; i < 4; ++i) {
                #pragma unroll
                for (int r = 0; r < 4; ++r) {
                    int lr = wrow + i * 16 + q * 4 + r;
                    float vle = acc[i][j][r];
                    if constexpr (EPI == 0) vle += cb;
                    else if constexpr (EPI == 1) vle += bias[bx * 128 + lr];
                    else if constexpr (EPI == 2) vle *= scale;
                    Ts[lr * 128 + (lc ^ (q << 3))] = f2bf(vle);
                }
            }
        }
        __syncthreads();
        unsigned short* Dp = (unsigned short*)Dv +
            (size_t)bz * sD + (size_t)(bx * 128) * ldd + by * 128;
        #pragma unroll
        for (int k = 0; k < 8; ++k) {
            int flat = k * 2048 + tid * 8;          // shorts, 8-aligned
            int rr = flat >> 7, cc = flat & 127;
            int key = (rr >> 2) & 3;
            short8 vv = *(const short8*)&Ts[flat ^ (key << 3)];
            *(short8*)&Dp[(size_t)rr * ldd + cc] = vv;
        }
    } else {
        // fp32 + residual: two 128x64 half-tiles (32 KB each pass).
        // Waves with w&1==h own half h's columns.
        float* Ts32 = (float*)&smem[0][0];          // 8192 floats
        float* Dp = (float*)Dv + (size_t)bz * sD + (size_t)(bx * 128) * ldd + by * 128;
        const float* Ap = aux + (size_t)bz * sAux + (size_t)(bx * 128) * ldd + by * 128;
        #pragma unroll
        for (int h = 0; h < 2; ++h) {
            if (h) __syncthreads();                 // half-0 copy-out done
            if ((w & 1) == h) {
                #pragma unroll
                for (int j = 0; j < 4; ++j) {
                    int lch = j * 16 + lm;          // 0..63 within half
                    #pragma unroll
                    for (int i = 0; i < 4; ++i) {
                        #pragma unroll
                        for (int r = 0; r < 4; ++r) {
                            int lr = wrow + i * 16 + q * 4 + r;
                            Ts32[lr * 64 + (lch ^ (q << 3))] =
                                acc[i][j][r] + bias[bx * 128 + lr];
                        }
                    }
                }
            }
            __syncthreads();
            #pragma unroll
            for (int k = 0; k < 8; ++k) {
                int flat = k * 1024 + tid * 4;      // floats, 4-aligned
                int rr = flat >> 6, cc = flat & 63;
                int key = (rr >> 2) & 3;
                f32x4 vv = *(const f32x4*)&Ts32[flat ^ (key << 3)];
                size_t go = (size_t)rr * ldd + h * 64 + cc;
                f32x4 av = *(const f32x4*)&Ap[go];
                *(f32x4*)&Dp[go] = vv + av;
            }
        }
    }
}

// ---------------------------------------------------------------------------
// Softmax: in-place on bf16 scores. One WAVE per row (16 elems/lane),
// shuffle reductions, no barriers. Block = 4 waves = 4 rows.
// ---------------------------------------------------------------------------
__global__ __launch_bounds__(256) void softmax_kernel(
    unsigned short* __restrict__ sc, long sSc)
{
    int bz = blockIdx.y;
    int row = blockIdx.x * 4 + (threadIdx.x >> 6);
    int lane = threadIdx.x & 63;
    unsigned short* p = sc + (size_t)bz * sSc + (size_t)row * N_ + lane * 16;

    short8 s0 = *(const short8*)p;
    short8 s1 = *(const short8*)(p + 8);
    float v[16];
    #pragma unroll
    for (int i = 0; i < 8; ++i) {
        v[i]     = bf2f((unsigned short)s0[i]);
        v[8 + i] = bf2f((unsigned short)s1[i]);
    }
    float m = v[0];
    #pragma unroll
    for (int i = 1; i < 16; ++i) m = fmaxf(m, v[i]);
    #pragma unroll
    for (int off = 32; off > 0; off >>= 1) m = fmaxf(m, __shfl_xor(m, off, 64));

    float sum = 0.f;
    #pragma unroll
    for (int i = 0; i < 16; ++i) { v[i] = __expf(v[i] - m); sum += v[i]; }
    #pragma unroll
    for (int off = 32; off > 0; off >>= 1) sum += __shfl_xor(sum, off, 64);
    float inv = 1.f / sum;

    short8 o0, o1;
    #pragma unroll
    for (int i = 0; i < 8; ++i) {
        o0[i] = (short)f2bf(v[i] * inv);
        o1[i] = (short)f2bf(v[8 + i] * inv);
    }
    *(short8*)p = o0;
    *(short8*)(p + 8) = o1;
}

// ---------------------------------------------------------------------------
extern "C" void kernel_launch(void* const* d_in, const int* in_sizes, int n_in,
                              void* d_out, int out_size, void* d_ws, size_t ws_size,
                              hipStream_t stream) {
    const float* x      = (const float*)d_in[0];
    const float* norm_w = (const float*)d_in[1];
    const float* norm_b = (const float*)d_in[2];
    const float* qkv_w  = (const float*)d_in[3];
    const float* qkv_b  = (const float*)d_in[4];
    const float* proj_w = (const float*)d_in[5];
    const float* proj_b = (const float*)d_in[6];
    float* out = (float*)d_out;

    // Fixed region: stats (8 KB) + bf16 weights (2 MB).
    char* ws = (char*)d_ws;
    float* stats = (float*)ws;
    unsigned short* wqkv  = (unsigned short*)(ws + 8192);   // 1536x512
    unsigned short* wproj = wqkv + (size_t)OC3_ * C_;       // 512x512
    char* base = (char*)(wproj + (size_t)C_ * C_);
    const size_t fixed = 8192 + (size_t)OC3_ * C_ * 2 + (size_t)C_ * C_ * 2;

    // Per-batch aliased region: 6 MB.
    //   [0,2M)  qkT bf16 [n][1024]
    //   [2,3M)  v bf16 [c][n]
    //   [3,4M)  hhatT bf16 [n][c]  -> after GEMM2 reused as houtT bf16 [n][c]
    //   [4,6M)  sc bf16 [n][m]     -> softmax in-place -> attn
    const size_t REG = 6u << 20;
    const long RSH = (long)(REG / 2);         // region stride in shorts

    size_t avail = ws_size > fixed ? ws_size - fixed : 0;
    int chunk = (int)(avail / REG);
    if (chunk < 1) chunk = 1;
    if (chunk > B_) chunk = B_;

    gn_stats_kernel<<<dim3(B_ * G_), dim3(256), 0, stream>>>(x, stats);
    cvt_bf16_kernel<<<dim3((OC3_ * C_ / 4 + 255) / 256), dim3(256), 0, stream>>>(
        qkv_w, wqkv, OC3_ * C_ / 4);
    cvt_bf16_kernel<<<dim3((C_ * C_ / 4 + 255) / 256), dim3(256), 0, stream>>>(
        proj_w, wproj, C_ * C_ / 4);

    const float scale = 0.044194173824159216f;  // 512^-0.5

    unsigned short* qkT   = (unsigned short*)base;
    unsigned short* vbuf  = (unsigned short*)(base + (2u << 20));
    unsigned short* hhatT = (unsigned short*)(base + (3u << 20));
    unsigned short* houtT = (unsigned short*)(base + (3u << 20)); // aliases hhatT
    unsigned short* sc    = (unsigned short*)(base + (4u << 20)); // scores/attn

    for (int b0 = 0; b0 < B_; b0 += chunk) {
        int nb = B_ - b0 < chunk ? B_ - b0 : chunk;

        hhatT_kernel<<<dim3(N_/64, C_/64, nb), dim3(256), 0, stream>>>(
            x, stats, norm_w, norm_b, hhatT, RSH, b0);

        // GEMM1a: qkT[n][o] = hhatT[n][:] . Wqk[o][:]   (o in [0,1024))
        gemm128<0><<<dim3(8 * 8 * nb), dim3(256), 0, stream>>>(
            hhatT, RSH, C_,  wqkv, 0, C_,
            qkT, RSH, 1024,  qkv_b, nullptr, 0, C_, 0.f, 8, 8, nb);

        // GEMM1b: v[c][n] = Wv[c][:] . hhatT[n][:]
        gemm128<1><<<dim3(4 * 8 * nb), dim3(256), 0, stream>>>(
            wqkv + (size_t)1024 * C_, 0, C_,  hhatT, RSH, C_,
            vbuf, RSH, N_,  qkv_b + 1024, nullptr, 0, C_, 0.f, 4, 8, nb);

        // GEMM2: sc[n][m] = bf16( scale * qkT[n][0:512] . qkT[m][512:1024] )
        gemm128<2><<<dim3(8 * 8 * nb), dim3(256), 0, stream>>>(
            qkT, RSH, 1024,  qkT + 512, RSH, 1024,
            sc, RSH, N_,  nullptr, nullptr, 0, C_, scale, 8, 8, nb);

        softmax_kernel<<<dim3(N_/4, nb), dim3(256), 0, stream>>>(sc, RSH);

        // GEMM3: houtT[n][c] = attn[n][:] . v[c][:]   (K = 1024)
        gemm128<3><<<dim3(8 * 4 * nb), dim3(256), 0, stream>>>(
            sc, RSH, N_,  vbuf, RSH, N_,
            houtT, RSH, C_,  nullptr, nullptr, 0, N_, 0.f, 8, 4, nb);

        // GEMM4: out[o][n] = pw[o][:] . houtT[n][:] + pb[o] + x[o][n]
        gemm128<4><<<dim3(4 * 8 * nb), dim3(256), 0, stream>>>(
            wproj, 0, C_,  houtT, RSH, C_,
            out + (size_t)b0 * C_ * N_, (long)C_ * N_, N_,
            proj_b, x + (size_t)b0 * C_ * N_, (long)C_ * N_, C_, 0.f, 4, 8, nb);
    }
}